// Round 6
// baseline (84.434 us; speedup 1.0000x reference)
//
#include <hip/hip_runtime.h>
#include <math.h>

#define B_ 32
#define M_ 64
#define N_ 5000
#define L_ 100
#define H_ 8
#define D_ 16
#define E_ 128
#define NBIN 1024
#define NI4 1250   // N_/4
#define NT 256     // threads per block = 4 waves, ONE ROW PER BLOCK

// ---- workspace float offsets ----
#define OFF_POSQ  0        // [8*100] layout [h][l]
#define OFF_C0    800      // [8]
#define OFF_C1    808      // [8]
#define OFF_C2    816      // [8]
#define OFF_PV0   824      // [128]
#define OFF_PV1   952      // [128]
#define OFF_PVB   1080     // [128]
#define OFF_WC0   1208     // [128]
#define OFF_WC1   1336     // [128]
#define OFF_WCB   1464     // [128]
#define OFF_SB    1592     // [3]
#define OFF_PCB   1596     // [100]
#define OFF_PV    1696     // [100*128]  PV[l][hd]
#define OFF_PCT   14496    // [128*100]  PCt[hd][l]

__device__ __forceinline__ int vbin(float v) {
  if (!(v >= 0.f)) return 0;
  if (v >= 1.0f) return NBIN - 1;
  return (int)(v * (float)NBIN);
}
__device__ __forceinline__ unsigned int umap(float v) {
  unsigned int b = __float_as_uint(v);
  return (b & 0x80000000u) ? ~b : (b | 0x80000000u);
}
__device__ __forceinline__ float unmap(unsigned int u) {
  unsigned int b = (u & 0x80000000u) ? (u ^ 0x80000000u) : ~u;
  return __uint_as_float(b);
}
// 1024 bins, 4 bins/thread: scan reads hist[(k<<8)|tid] -> stride-1 across lanes
#define HMAPA(b) ((((b) & 3) << 8) | ((b) >> 2))

// ---- fused precomp: block 0 = q-folded vectors; blocks 1..100 = per-l tables ----
__global__ __launch_bounds__(128) void precomp(
    const float* __restrict__ Wq, const float* __restrict__ Wk,
    const float* __restrict__ cur, const float* __restrict__ Wi,
    const float* __restrict__ bi, const float* __restrict__ Wv,
    const float* __restrict__ Wc, const float* __restrict__ bc,
    float* __restrict__ ws)
{
  const int tid = threadIdx.x;
  const int blk = blockIdx.x;
  __shared__ float pr[E_];
  __shared__ float red[8];
  const int lane = tid & 63, wvv = tid >> 6;

  if (blk == 0) {
    float qsv = 0.f;
    for (int e = 0; e < E_; ++e) qsv = fmaf(Wq[tid * E_ + e], cur[e], qsv);
    float wk0=0,wk1=0,wkb=0,pv0=0,pv1=0,pvb=0,wc0=0,wc1=0,wcb=0;
    for (int e = 0; e < E_; ++e) {
      float wi0 = Wi[2*e], wi1 = Wi[2*e+1], bie = bi[e];
      float wk = Wk[tid*E_+e], wvx = Wv[tid*E_+e], wcc = Wc[e*(H_*D_)+tid];
      wk0=fmaf(wk,wi0,wk0);  wk1=fmaf(wk,wi1,wk1);  wkb=fmaf(wk,bie,wkb);
      pv0=fmaf(wvx,wi0,pv0); pv1=fmaf(wvx,wi1,pv1); pvb=fmaf(wvx,bie,pvb);
      wc0=fmaf(wcc,wi0,wc0); wc1=fmaf(wcc,wi1,wc1); wcb=fmaf(wcc,bie,wcb);
    }
    ws[OFF_PV0+tid]=pv0; ws[OFF_PV1+tid]=pv1; ws[OFF_PVB+tid]=pvb;
    ws[OFF_WC0+tid]=wc0; ws[OFF_WC1+tid]=wc1; ws[OFF_WCB+tid]=wcb;
    float c0 = qsv*wk0, c1 = qsv*wk1, c2 = qsv*wkb;
    for (int off = 1; off < 16; off <<= 1) {
      c0 += __shfl_xor(c0, off, 16); c1 += __shfl_xor(c1, off, 16); c2 += __shfl_xor(c2, off, 16);
    }
    if ((tid & 15) == 0) {
      int h = tid >> 4;
      ws[OFF_C0+h] = c0*0.25f; ws[OFF_C1+h] = c1*0.25f; ws[OFF_C2+h] = c2*0.25f;
    }
    float p0 = Wi[2*tid]*bc[tid], p1 = Wi[2*tid+1]*bc[tid], p2 = bi[tid]*bc[tid];
    for (int off = 32; off > 0; off >>= 1) {
      p0 += __shfl_xor(p0, off, 64); p1 += __shfl_xor(p1, off, 64); p2 += __shfl_xor(p2, off, 64);
    }
    if (lane == 0) { red[wvv*3+0]=p0; red[wvv*3+1]=p1; red[wvv*3+2]=p2; }
    __syncthreads();
    if (tid == 0) {
      ws[OFF_SB+0]=red[0]+red[3]; ws[OFF_SB+1]=red[1]+red[4]; ws[OFF_SB+2]=red[2]+red[5];
    }
  } else {
    const int l = blk - 1;
    const float log_inc = 0.14619588050755848f;   // ln(10000)/63
    {
      int j = tid & 63;
      float scaled = (float)l * expf(-(float)j * log_inc);
      pr[tid] = (tid < 64) ? sinf(scaled) : cosf(scaled);
    }
    __syncthreads();
    float qsv=0.f, pwk=0.f, accv=0.f, accc=0.f;
    for (int e = 0; e < E_; ++e) qsv = fmaf(Wq[tid*E_+e], cur[e], qsv);
    for (int e = 0; e < E_; ++e) {
      float p = pr[e];
      pwk  = fmaf(Wk[tid*E_+e], p, pwk);
      accv = fmaf(Wv[tid*E_+e], p, accv);
      accc = fmaf(Wc[e*(H_*D_)+tid], p, accc);
    }
    ws[OFF_PV  + l*(H_*D_) + tid] = accv;
    ws[OFF_PCT + tid*L_ + l] = accc;
    float pq = qsv * pwk;
    for (int off = 1; off < 16; off <<= 1) pq += __shfl_xor(pq, off, 16);
    if ((tid & 15) == 0) ws[OFF_POSQ + (tid>>4)*L_ + l] = pq * 0.25f;
    float pb = pr[tid] * bc[tid];
    for (int off = 32; off > 0; off >>= 1) pb += __shfl_xor(pb, off, 64);
    if (lane == 0) red[wvv] = pb;
    __syncthreads();
    if (tid == 0) ws[OFF_PCB + l] = red[0] + red[1];
  }
}

// ---- main kernel: one block (4 waves) per row ----
__global__ __launch_bounds__(NT, 8) void local_att_kernel(
    const float* __restrict__ dist, const float* __restrict__ theta,
    const float* __restrict__ ninf, const float* __restrict__ ws,
    float* __restrict__ out)
{
  __shared__ unsigned int hist[NBIN];           // 4 KB
  __shared__ unsigned long long sel[128];       // 1 KB
  __shared__ float sdv[128];
  __shared__ unsigned int idxs[128];
  __shared__ float stv[128], smv[128];
  __shared__ float att[H_ * D_];
  __shared__ unsigned int bitmap[160];          // 5000 bits
  __shared__ unsigned int hidx[256];
  __shared__ float hval[256];
  __shared__ unsigned int wsum[4];
  __shared__ unsigned int s_bstar, s_cumB, s_binc, s_cnt, s_chosen, s_cumb2;

  const int tid = threadIdx.x;
  const int lane = tid & 63, wv = tid >> 6;
  const size_t base = (size_t)blockIdx.x * N_;
  const float4* d4 = (const float4*)(dist + base);
  const float4* n4 = (const float4*)(ninf + base);

  // ---- P0: init ----
  for (int j = tid; j < NBIN; j += NT) hist[j] = 0u;
  if (tid < 128) sel[tid] = ~0ull;
  if (tid == 0) s_cnt = 0u;
  __syncthreads();

  // ---- P1: stream row once; keep u in regs; LDS histogram ----
  unsigned int u[20];
#pragma unroll
  for (int t = 0; t < 5; ++t) {
    int i4 = tid + NT * t;
    if (i4 < NI4) {
      float4 dv = d4[i4], nv = n4[i4];
#pragma unroll
      for (int c = 0; c < 4; ++c) {
        float v = (&dv.x)[c] - (&nv.x)[c];
        u[4 * t + c] = umap(v);
        atomicAdd(&hist[HMAPA(vbin(v))], 1u);
      }
    }
  }
  __syncthreads();

  // ---- P2: cross-wave scan of 1024 bins (4/thread), pick pivot bin ----
  {
    unsigned int h4[4]; unsigned int s = 0;
#pragma unroll
    for (int k = 0; k < 4; ++k) { h4[k] = hist[(k << 8) | tid]; s += h4[k]; }
    unsigned int v = s;
#pragma unroll
    for (int off = 1; off < 64; off <<= 1) {
      unsigned int x = __shfl_up(v, off, 64);
      if (lane >= off) v += x;
    }
    if (lane == 63) wsum[wv] = v;
    __syncthreads();
    { unsigned int add = 0; for (int ww = 0; ww < wv; ++ww) add += wsum[ww]; v += add; }
    unsigned int cumBefore = v - s;
    if (cumBefore < (unsigned)L_ && v >= (unsigned)L_) {   // exactly one thread
      unsigned int c = cumBefore;
#pragma unroll
      for (int k = 0; k < 4; ++k) {
        unsigned int h = h4[k];
        if (c + h >= (unsigned)L_) { s_bstar = tid * 4 + k; s_cumB = c; s_binc = h; break; }
        c += h;
      }
    }
    __syncthreads();
  }
  const int bstar = (int)s_bstar;
  const bool fb = (s_cumB + s_binc > 128u);

  // ---- P3: compaction from REGISTERS (common) or exact radix fallback (rare) ----
  if (!fb) {
#pragma unroll
    for (int t = 0; t < 5; ++t) {
      int i4 = tid + NT * t;
      if (i4 < NI4) {
#pragma unroll
        for (int c = 0; c < 4; ++c) {
          unsigned int uu = u[4 * t + c];
          if (vbin(unmap(uu)) <= bstar) {     // exactly consistent with histogram
            unsigned int p = atomicAdd(&s_cnt, 1u);
            if (p < 128u) sel[p] = ((unsigned long long)uu << 16) | (unsigned)(4 * i4 + c);
          }
        }
      }
    }
  } else {
    unsigned long long prefix = 0ull;
    unsigned int Krem = L_;
    for (int pass = 0; pass < 6; ++pass) {
      const int shift = 40 - 8 * pass;
      hist[tid] = 0u;                          // NT==256 bins
      __syncthreads();
#pragma unroll
      for (int t = 0; t < 5; ++t) {
        int i4 = tid + NT * t;
        if (i4 < NI4) {
#pragma unroll
          for (int c = 0; c < 4; ++c) {
            unsigned long long key = ((unsigned long long)u[4 * t + c] << 16) | (unsigned)(4 * i4 + c);
            if ((key >> (shift + 8)) == prefix)
              atomicAdd(&hist[(unsigned)(key >> shift) & 0xFFu], 1u);
          }
        }
      }
      __syncthreads();
      unsigned int s = hist[tid];              // bin == tid
      unsigned int v = s;
#pragma unroll
      for (int off = 1; off < 64; off <<= 1) {
        unsigned int x = __shfl_up(v, off, 64);
        if (lane >= off) v += x;
      }
      if (lane == 63) wsum[wv] = v;
      __syncthreads();
      { unsigned int add = 0; for (int ww = 0; ww < wv; ++ww) add += wsum[ww]; v += add; }
      unsigned int cb = v - s;
      if (cb < Krem && v >= Krem) { s_chosen = (unsigned)tid; s_cumb2 = cb; }
      __syncthreads();
      prefix = (prefix << 8) | s_chosen;
      Krem -= s_cumb2;
      __syncthreads();
    }
    const unsigned long long kpiv = prefix;
#pragma unroll
    for (int t = 0; t < 5; ++t) {
      int i4 = tid + NT * t;
      if (i4 < NI4) {
#pragma unroll
        for (int c = 0; c < 4; ++c) {
          unsigned long long key = ((unsigned long long)u[4 * t + c] << 16) | (unsigned)(4 * i4 + c);
          if (key <= kpiv) {
            unsigned int p = atomicAdd(&s_cnt, 1u);
            if (p < 128u) sel[p] = key;
          }
        }
      }
    }
  }
  __syncthreads();

  // ---- P4: fused rank-sort + theta/ninf gather (loads hide under rank loop);
  //          waves 2/3 init bitmap + hash ----
  if (tid < 128) {
    unsigned long long ka = sel[tid];
    const bool valid = (ka != ~0ull);
    unsigned int ix = (unsigned int)(ka & 0xFFFFull);
    float th = 0.f, nm = 0.f;
    if (valid) { th = theta[base + ix]; nm = ninf[base + ix]; }
    int ra = 0;
#pragma unroll 8
    for (int j = 0; j < 128; ++j) ra += (sel[j] < ka) ? 1 : 0;
    if (valid) {
      sdv[ra] = unmap((unsigned int)(ka >> 16));
      idxs[ra] = ix;
      stv[ra] = th;
      smv[ra] = nm;
    }
  } else if (tid < 192) {
    for (int j = tid - 128; j < 160; j += 64) bitmap[j] = 0u;
  } else {
    for (int j = tid - 192; j < 256; j += 64) hidx[j] = 0xFFFFFFFFu;
  }
  __syncthreads();

  // ---- P5: score + softmax + att, 16 lanes per head on tid<128 ----
  const float invn = 1.0f / (sdv[L_ - 1] + 1e-6f);
  if (tid < 128) {
    const int hh = tid >> 4, jj = tid & 15;
    float w7[7];
    float a0, a1;
    {
      const float c0 = ws[OFF_C0 + hh], c1 = ws[OFF_C1 + hh], c2 = ws[OFF_C2 + hh];
      float mx = -INFINITY;
#pragma unroll
      for (int k = 0; k < 7; ++k) {
        int l = jj + 16 * k;
        float scv = -INFINITY;
        if (l < L_)
          scv = fmaf(sdv[l] * invn, c0, fmaf(stv[l], c1, c2 + ws[OFF_POSQ + hh * L_ + l] + smv[l]));
        w7[k] = scv;
        mx = fmaxf(mx, scv);
      }
#pragma unroll
      for (int off = 1; off <= 8; off <<= 1) mx = fmaxf(mx, __shfl_xor(mx, off, 64));
      float sum = 0.f;
#pragma unroll
      for (int k = 0; k < 7; ++k) { float e = expf(w7[k] - mx); w7[k] = e; sum += e; }
#pragma unroll
      for (int off = 1; off <= 8; off <<= 1) sum += __shfl_xor(sum, off, 64);
      const float inv = 1.0f / sum;
      a0 = 0.f; a1 = 0.f;
#pragma unroll
      for (int k = 0; k < 7; ++k) {
        int l = jj + 16 * k; int lc = (l < L_) ? l : 0;
        float wgt = w7[k] * inv; w7[k] = wgt;
        a0 = fmaf(wgt, sdv[lc] * invn, a0);
        a1 = fmaf(wgt, stv[lc], a1);
      }
#pragma unroll
      for (int off = 1; off <= 8; off <<= 1) { a0 += __shfl_xor(a0, off, 64); a1 += __shfl_xor(a1, off, 64); }
    }
    {
      float part[16];
#pragma unroll
      for (int t = 0; t < 16; ++t) part[t] = 0.f;
#pragma unroll
      for (int k = 0; k < 7; ++k) {
        int l = jj + 16 * k;
        if (l < L_) {
          const float* pv = ws + OFF_PV + l * (H_ * D_) + hh * 16;
          float wgt = w7[k];
#pragma unroll
          for (int t = 0; t < 16; ++t) part[t] = fmaf(wgt, pv[t], part[t]);
        }
      }
#pragma unroll
      for (int off = 1; off <= 8; off <<= 1) {
#pragma unroll
        for (int t = 0; t < 16; ++t) part[t] += __shfl_xor(part[t], off, 64);
      }
#pragma unroll
      for (int t = 0; t < 16; ++t) {   // 16 lanes write same value to same addr
        int hd = hh * 16 + t;
        att[hd] = fmaf(a0, ws[OFF_PV0 + hd], fmaf(a1, ws[OFF_PV1 + hd], ws[OFF_PVB + hd])) + part[t];
      }
    }
  }
  __syncthreads();

  // ---- P6: m0/m1/mb (redundant in waves 0/1, 64-wide reduce over att) ----
  float m0 = 0.f, m1 = 0.f, mb = 0.f;
  if (tid < 128) {
    float x0 = att[lane], x1 = att[lane + 64];
    m0 = fmaf(x0, ws[OFF_WC0 + lane], x1 * ws[OFF_WC0 + lane + 64]);
    m1 = fmaf(x0, ws[OFF_WC1 + lane], x1 * ws[OFF_WC1 + lane + 64]);
    mb = fmaf(x0, ws[OFF_WCB + lane], x1 * ws[OFF_WCB + lane + 64]);
#pragma unroll
    for (int off = 1; off < 64; off <<= 1) {
      m0 += __shfl_xor(m0, off, 64);
      m1 += __shfl_xor(m1, off, 64);
      mb += __shfl_xor(mb, off, 64);
    }
    m0 += ws[OFF_SB + 0]; m1 += ws[OFF_SB + 1]; mb += ws[OFF_SB + 2];
  }

  // ---- P7: s2[l], insert into hash + bitmap ----
  if (tid < L_) {
    float acc = ws[OFF_PCB + tid];
#pragma unroll 8
    for (int hd = 0; hd < H_ * D_; ++hd) acc = fmaf(att[hd], ws[OFF_PCT + hd * L_ + tid], acc);
    const float SC = 0.08838834764831845f;   // 1/sqrt(E)
    float s2v = (fmaf(sdv[tid] * invn, m0, fmaf(stv[tid], m1, mb)) + acc) * SC;
    unsigned int idx = idxs[tid];
    unsigned int p = idx & 255u;
    while (atomicCAS(&hidx[p], 0xFFFFFFFFu, idx) != 0xFFFFFFFFu) p = (p + 1) & 255u;
    hval[p] = s2v;
    atomicOr(&bitmap[idx >> 5], 1u << (idx & 31));
  }
  __syncthreads();

  // ---- P8: fused zero+scatter coalesced write (each line written once) ----
  float4* o4 = (float4*)(out + base);
#pragma unroll
  for (int t = 0; t < 5; ++t) {
    int i4 = tid + NT * t;
    if (i4 < NI4) {
      unsigned int wbits = (bitmap[i4 >> 3] >> ((i4 & 7) * 4)) & 0xFu;
      float4 o = make_float4(0.f, 0.f, 0.f, 0.f);
      if (wbits) {
#pragma unroll
        for (int c = 0; c < 4; ++c) {
          if ((wbits >> c) & 1u) {
            unsigned int idx = (unsigned int)(4 * i4 + c);
            unsigned int p = idx & 255u;
            while (hidx[p] != idx) p = (p + 1) & 255u;
            (&o.x)[c] = hval[p];
          }
        }
      }
      o4[i4] = o;
    }
  }
}

extern "C" void kernel_launch(void* const* d_in, const int* in_sizes, int n_in,
                              void* d_out, int out_size, void* d_ws, size_t ws_size,
                              hipStream_t stream) {
  const float* dist = (const float*)d_in[0];
  const float* theta = (const float*)d_in[1];
  const float* ninf = (const float*)d_in[2];
  const float* Wi   = (const float*)d_in[3];
  const float* bi   = (const float*)d_in[4];
  const float* cur  = (const float*)d_in[5];
  const float* Wq   = (const float*)d_in[6];
  const float* Wk   = (const float*)d_in[7];
  const float* Wv   = (const float*)d_in[8];
  const float* Wc   = (const float*)d_in[9];
  const float* bcv  = (const float*)d_in[10];
  float* out = (float*)d_out;
  float* ws  = (float*)d_ws;

  precomp<<<dim3(L_ + 1), dim3(128), 0, stream>>>(Wq, Wk, cur, Wi, bi, Wv, Wc, bcv, ws);
  local_att_kernel<<<dim3(B_ * M_), dim3(NT), 0, stream>>>(dist, theta, ninf, ws, out);
}

// Round 7
// 73.150 us; speedup vs baseline: 1.1543x; 1.1543x over previous
//
#include <hip/hip_runtime.h>
#include <math.h>

#define B_ 32
#define M_ 64
#define N_ 5000
#define L_ 100
#define H_ 8
#define D_ 16
#define E_ 128
#define NBIN 1024
#define NI4 1250   // N_/4
#define NT 128     // 2 waves, ONE ROW PER BLOCK

// ---- workspace float offsets ----
#define OFF_POSQ  0        // [8*100] layout [h][l]
#define OFF_C0    800      // [8]
#define OFF_C1    808      // [8]
#define OFF_C2    816      // [8]
#define OFF_PV0   824      // [128]
#define OFF_PV1   952      // [128]
#define OFF_PVB   1080     // [128]
#define OFF_WC0   1208     // [128]
#define OFF_WC1   1336     // [128]
#define OFF_WCB   1464     // [128]
#define OFF_SB    1592     // [3]
#define OFF_PCB   1596     // [100]
#define OFF_PV    1696     // [100*128]  PV[l][hd]
#define OFF_PCT   14496    // [128*100]  PCt[hd][l]

__device__ __forceinline__ int vbin(float v) {
  if (!(v >= 0.f)) return 0;
  if (v >= 1.0f) return NBIN - 1;
  return (int)(v * (float)NBIN);
}
__device__ __forceinline__ unsigned int umap(float v) {
  unsigned int b = __float_as_uint(v);
  return (b & 0x80000000u) ? ~b : (b | 0x80000000u);
}
__device__ __forceinline__ float unmap(unsigned int u) {
  unsigned int b = (u & 0x80000000u) ? (u ^ 0x80000000u) : ~u;
  return __uint_as_float(b);
}
// 1024 bins, 8 bins/thread (128 thr): scan reads hist[(k<<7)|tid] stride-1
#define HMAP8(b) ((((b) & 7) << 7) | ((b) >> 3))

// ---- fused precomp: block 0 = q-folded vectors; blocks 1..100 = per-l tables ----
__global__ __launch_bounds__(128) void precomp(
    const float* __restrict__ Wq, const float* __restrict__ Wk,
    const float* __restrict__ cur, const float* __restrict__ Wi,
    const float* __restrict__ bi, const float* __restrict__ Wv,
    const float* __restrict__ Wc, const float* __restrict__ bc,
    float* __restrict__ ws)
{
  const int tid = threadIdx.x;
  const int blk = blockIdx.x;
  __shared__ float pr[E_];
  __shared__ float red[8];
  const int lane = tid & 63, wvv = tid >> 6;

  if (blk == 0) {
    float qsv = 0.f;
    for (int e = 0; e < E_; ++e) qsv = fmaf(Wq[tid * E_ + e], cur[e], qsv);
    float wk0=0,wk1=0,wkb=0,pv0=0,pv1=0,pvb=0,wc0=0,wc1=0,wcb=0;
    for (int e = 0; e < E_; ++e) {
      float wi0 = Wi[2*e], wi1 = Wi[2*e+1], bie = bi[e];
      float wk = Wk[tid*E_+e], wvx = Wv[tid*E_+e], wcc = Wc[e*(H_*D_)+tid];
      wk0=fmaf(wk,wi0,wk0);  wk1=fmaf(wk,wi1,wk1);  wkb=fmaf(wk,bie,wkb);
      pv0=fmaf(wvx,wi0,pv0); pv1=fmaf(wvx,wi1,pv1); pvb=fmaf(wvx,bie,pvb);
      wc0=fmaf(wcc,wi0,wc0); wc1=fmaf(wcc,wi1,wc1); wcb=fmaf(wcc,bie,wcb);
    }
    ws[OFF_PV0+tid]=pv0; ws[OFF_PV1+tid]=pv1; ws[OFF_PVB+tid]=pvb;
    ws[OFF_WC0+tid]=wc0; ws[OFF_WC1+tid]=wc1; ws[OFF_WCB+tid]=wcb;
    float c0 = qsv*wk0, c1 = qsv*wk1, c2 = qsv*wkb;
    for (int off = 1; off < 16; off <<= 1) {
      c0 += __shfl_xor(c0, off, 16); c1 += __shfl_xor(c1, off, 16); c2 += __shfl_xor(c2, off, 16);
    }
    if ((tid & 15) == 0) {
      int h = tid >> 4;
      ws[OFF_C0+h] = c0*0.25f; ws[OFF_C1+h] = c1*0.25f; ws[OFF_C2+h] = c2*0.25f;
    }
    float p0 = Wi[2*tid]*bc[tid], p1 = Wi[2*tid+1]*bc[tid], p2 = bi[tid]*bc[tid];
    for (int off = 32; off > 0; off >>= 1) {
      p0 += __shfl_xor(p0, off, 64); p1 += __shfl_xor(p1, off, 64); p2 += __shfl_xor(p2, off, 64);
    }
    if (lane == 0) { red[wvv*3+0]=p0; red[wvv*3+1]=p1; red[wvv*3+2]=p2; }
    __syncthreads();
    if (tid == 0) {
      ws[OFF_SB+0]=red[0]+red[3]; ws[OFF_SB+1]=red[1]+red[4]; ws[OFF_SB+2]=red[2]+red[5];
    }
  } else {
    const int l = blk - 1;
    const float log_inc = 0.14619588050755848f;   // ln(10000)/63
    {
      int j = tid & 63;
      float scaled = (float)l * expf(-(float)j * log_inc);
      pr[tid] = (tid < 64) ? sinf(scaled) : cosf(scaled);
    }
    __syncthreads();
    float qsv=0.f, pwk=0.f, accv=0.f, accc=0.f;
    for (int e = 0; e < E_; ++e) qsv = fmaf(Wq[tid*E_+e], cur[e], qsv);
    for (int e = 0; e < E_; ++e) {
      float p = pr[e];
      pwk  = fmaf(Wk[tid*E_+e], p, pwk);
      accv = fmaf(Wv[tid*E_+e], p, accv);
      accc = fmaf(Wc[e*(H_*D_)+tid], p, accc);
    }
    ws[OFF_PV  + l*(H_*D_) + tid] = accv;
    ws[OFF_PCT + tid*L_ + l] = accc;
    float pq = qsv * pwk;
    for (int off = 1; off < 16; off <<= 1) pq += __shfl_xor(pq, off, 16);
    if ((tid & 15) == 0) ws[OFF_POSQ + (tid>>4)*L_ + l] = pq * 0.25f;
    float pb = pr[tid] * bc[tid];
    for (int off = 32; off > 0; off >>= 1) pb += __shfl_xor(pb, off, 64);
    if (lane == 0) red[wvv] = pb;
    __syncthreads();
    if (tid == 0) ws[OFF_PCB + l] = red[0] + red[1];
  }
}

// ---- main kernel: one block (2 waves) per row ----
__global__ __launch_bounds__(NT, 4) void local_att_kernel(
    const float* __restrict__ dist, const float* __restrict__ theta,
    const float* __restrict__ ninf, const float* __restrict__ ws,
    float* __restrict__ out)
{
  __shared__ unsigned int hist[NBIN];           // 4 KB
  __shared__ union alignas(16) {
    unsigned short bins[N_];                    // P1..P3 (10 KB)
    struct { unsigned int bitmap[160]; unsigned int hidx[256]; float hval[256]; } o;  // P6..P9
  } bu;
  __shared__ unsigned long long sel[128];       // 1 KB
  __shared__ float sdv[128];
  __shared__ unsigned int idxs[128];
  __shared__ float stv[128], smv[128];
  __shared__ float att[H_ * D_];
  __shared__ unsigned int wsum[2];
  __shared__ unsigned int s_bstar, s_cumB, s_binc, s_cnt, s_chosen, s_cumb2;

  const int tid = threadIdx.x;
  const int lane = tid & 63, wv = tid >> 6;
  const size_t base = (size_t)blockIdx.x * N_;
  const float4* d4 = (const float4*)(dist + base);
  const float4* n4 = (const float4*)(ninf + base);

  // ---- P0: init ----
  for (int j = tid; j < NBIN; j += NT) hist[j] = 0u;
  sel[tid] = ~0ull;
  if (tid == 0) s_cnt = 0u;
  __syncthreads();

  // ---- P1: stream row once, 5-deep staged loads x2 chunks; u16 bins -> LDS ----
#pragma unroll
  for (int ch = 0; ch < 2; ++ch) {
    float4 dr[5], nr[5];
#pragma unroll
    for (int t = 0; t < 5; ++t) {
      int i4 = tid + NT * (5 * ch + t);
      if (i4 < NI4) { dr[t] = d4[i4]; nr[t] = n4[i4]; }
    }
#pragma unroll
    for (int t = 0; t < 5; ++t) {
      int i4 = tid + NT * (5 * ch + t);
      if (i4 < NI4) {
        unsigned int bn[4];
#pragma unroll
        for (int c = 0; c < 4; ++c) {
          float v = (&dr[t].x)[c] - (&nr[t].x)[c];
          bn[c] = (unsigned int)vbin(v);
          atomicAdd(&hist[HMAP8(bn[c])], 1u);
        }
        uint2 pk;
        pk.x = bn[0] | (bn[1] << 16);
        pk.y = bn[2] | (bn[3] << 16);
        *(uint2*)&bu.bins[4 * i4] = pk;
      }
    }
  }
  __syncthreads();

  // ---- P2: cross-wave scan of 1024 bins (8/thread), pick pivot bin ----
  {
    unsigned int h8[8]; unsigned int s = 0;
#pragma unroll
    for (int k = 0; k < 8; ++k) { h8[k] = hist[(k << 7) | tid]; s += h8[k]; }
    unsigned int v = s;
#pragma unroll
    for (int off = 1; off < 64; off <<= 1) {
      unsigned int x = __shfl_up(v, off, 64);
      if (lane >= off) v += x;
    }
    if (lane == 63) wsum[wv] = v;
    __syncthreads();
    if (wv == 1) v += wsum[0];
    unsigned int cumBefore = v - s;
    if (cumBefore < (unsigned)L_ && v >= (unsigned)L_) {   // exactly one thread
      unsigned int c = cumBefore;
#pragma unroll
      for (int k = 0; k < 8; ++k) {
        unsigned int h = h8[k];
        if (c + h >= (unsigned)L_) { s_bstar = tid * 8 + k; s_cumB = c; s_binc = h; break; }
        c += h;
      }
    }
    __syncthreads();
  }
  const int bstar = (int)s_bstar;
  const bool fb = (s_cumB + s_binc > 128u);

  // ---- P3: compact via LDS bins + candidate reload (common) or exact radix (rare) ----
  if (!fb) {
#pragma unroll
    for (int t = 0; t < 10; ++t) {
      int i4 = tid + NT * t;
      if (i4 < NI4) {
        uint2 pk = *(const uint2*)&bu.bins[4 * i4];
        unsigned int b4[4] = {pk.x & 0xFFFFu, pk.x >> 16, pk.y & 0xFFFFu, pk.y >> 16};
#pragma unroll
        for (int c = 0; c < 4; ++c) {
          if ((int)b4[c] <= bstar) {
            int i = 4 * i4 + c;
            float v = dist[base + i] - ninf[base + i];   // bit-exact recompute (L3-hot)
            unsigned int p = atomicAdd(&s_cnt, 1u);
            if (p < 128u) sel[p] = ((unsigned long long)umap(v) << 16) | (unsigned)i;
          }
        }
      }
    }
  } else {
    // rare exact path: 6x8-bit composite radix, keys re-streamed from global
    unsigned long long prefix = 0ull;
    unsigned int Krem = L_;
    for (int pass = 0; pass < 6; ++pass) {
      const int shift = 40 - 8 * pass;
      for (int j = tid; j < 256; j += NT) hist[j] = 0u;
      __syncthreads();
      for (int t = 0; t < 10; ++t) {
        int i4 = tid + NT * t;
        if (i4 < NI4) {
          float4 dv = d4[i4], nv = n4[i4];
#pragma unroll
          for (int c = 0; c < 4; ++c) {
            float v = (&dv.x)[c] - (&nv.x)[c];
            unsigned long long key = ((unsigned long long)umap(v) << 16) | (unsigned)(4 * i4 + c);
            if ((key >> (shift + 8)) == prefix)
              atomicAdd(&hist[(unsigned)(key >> shift) & 0xFFu], 1u);
          }
        }
      }
      __syncthreads();
      unsigned int s0 = hist[2 * tid], s1 = hist[2 * tid + 1];
      unsigned int s = s0 + s1;
      unsigned int v = s;
#pragma unroll
      for (int off = 1; off < 64; off <<= 1) {
        unsigned int x = __shfl_up(v, off, 64);
        if (lane >= off) v += x;
      }
      if (lane == 63) wsum[wv] = v;
      __syncthreads();
      if (wv == 1) v += wsum[0];
      unsigned int cb = v - s;
      if (cb < Krem && v >= Krem) {
        if (cb + s0 >= Krem) { s_chosen = 2u * tid;     s_cumb2 = cb; }
        else                 { s_chosen = 2u * tid + 1; s_cumb2 = cb + s0; }
      }
      __syncthreads();
      prefix = (prefix << 8) | s_chosen;
      Krem -= s_cumb2;
      __syncthreads();
    }
    const unsigned long long kpiv = prefix;
    for (int t = 0; t < 10; ++t) {
      int i4 = tid + NT * t;
      if (i4 < NI4) {
        float4 dv = d4[i4], nv = n4[i4];
#pragma unroll
        for (int c = 0; c < 4; ++c) {
          float v = (&dv.x)[c] - (&nv.x)[c];
          unsigned long long key = ((unsigned long long)umap(v) << 16) | (unsigned)(4 * i4 + c);
          if (key <= kpiv) {
            unsigned int p = atomicAdd(&s_cnt, 1u);
            if (p < 128u) sel[p] = key;
          }
        }
      }
    }
  }
  __syncthreads();

  // ---- P4: fused rank-sort + theta/ninf gather (loads hide under rank loop) ----
  {
    unsigned long long ka = sel[tid];
    const bool valid = (ka != ~0ull);
    unsigned int ix = (unsigned int)(ka & 0xFFFFull);
    float th = 0.f, nm = 0.f;
    if (valid) { th = theta[base + ix]; nm = ninf[base + ix]; }
    int ra = 0;
#pragma unroll 8
    for (int j = 0; j < 128; ++j) ra += (sel[j] < ka) ? 1 : 0;
    if (valid) {
      sdv[ra] = unmap((unsigned int)(ka >> 16));
      idxs[ra] = ix;
      stv[ra] = th;
      smv[ra] = nm;
    }
  }
  __syncthreads();

  // ---- P5: wave0 = score/softmax/att; wave1 = init bitmap + hash ----
  const float invn = 1.0f / (sdv[L_ - 1] + 1e-6f);
  if (wv == 0) {
    const int hh = lane >> 3, jj = lane & 7;
    float w13[13];
    float a0, a1;
    {
      const float c0 = ws[OFF_C0 + hh], c1 = ws[OFF_C1 + hh], c2 = ws[OFF_C2 + hh];
      float mx = -INFINITY;
#pragma unroll
      for (int k = 0; k < 13; ++k) {
        int l = jj + 8 * k;
        float scv = -INFINITY;
        if (l < L_)
          scv = fmaf(sdv[l] * invn, c0, fmaf(stv[l], c1, c2 + ws[OFF_POSQ + hh * L_ + l] + smv[l]));
        w13[k] = scv;
        mx = fmaxf(mx, scv);
      }
#pragma unroll
      for (int off = 1; off <= 4; off <<= 1) mx = fmaxf(mx, __shfl_xor(mx, off, 64));
      float sum = 0.f;
#pragma unroll
      for (int k = 0; k < 13; ++k) { float e = expf(w13[k] - mx); w13[k] = e; sum += e; }
#pragma unroll
      for (int off = 1; off <= 4; off <<= 1) sum += __shfl_xor(sum, off, 64);
      const float inv = 1.0f / sum;
      a0 = 0.f; a1 = 0.f;
#pragma unroll
      for (int k = 0; k < 13; ++k) {
        int l = jj + 8 * k; int lc = (l < L_) ? l : 0;
        float wgt = w13[k] * inv; w13[k] = wgt;
        a0 = fmaf(wgt, sdv[lc] * invn, a0);
        a1 = fmaf(wgt, stv[lc], a1);
      }
#pragma unroll
      for (int off = 1; off <= 4; off <<= 1) { a0 += __shfl_xor(a0, off, 64); a1 += __shfl_xor(a1, off, 64); }
    }
    {
      float part[16];
#pragma unroll
      for (int t = 0; t < 16; ++t) part[t] = 0.f;
#pragma unroll
      for (int k = 0; k < 13; ++k) {
        int l = jj + 8 * k;
        if (l < L_) {
          const float* pv = ws + OFF_PV + l * (H_ * D_) + hh * 16;
          float wgt = w13[k];
#pragma unroll
          for (int t = 0; t < 16; ++t) part[t] = fmaf(wgt, pv[t], part[t]);
        }
      }
#pragma unroll
      for (int off = 1; off <= 4; off <<= 1) {
#pragma unroll
        for (int t = 0; t < 16; ++t) part[t] += __shfl_xor(part[t], off, 64);
      }
#pragma unroll
      for (int t = 0; t < 16; ++t) {   // 8 lanes write identical value to same addr
        int hd = hh * 16 + t;
        att[hd] = fmaf(a0, ws[OFF_PV0 + hd], fmaf(a1, ws[OFF_PV1 + hd], ws[OFF_PVB + hd])) + part[t];
      }
    }
  } else {
    for (int j = lane; j < 160; j += 64) bu.o.bitmap[j] = 0u;
    for (int j = lane; j < 256; j += 64) bu.o.hidx[j] = 0xFFFFFFFFu;
  }
  __syncthreads();

  // ---- P6: m0/m1/mb (both waves redundant, 64-wide reduce over att) ----
  float m0, m1, mb;
  {
    float x0 = att[lane], x1 = att[lane + 64];
    m0 = fmaf(x0, ws[OFF_WC0 + lane], x1 * ws[OFF_WC0 + lane + 64]);
    m1 = fmaf(x0, ws[OFF_WC1 + lane], x1 * ws[OFF_WC1 + lane + 64]);
    mb = fmaf(x0, ws[OFF_WCB + lane], x1 * ws[OFF_WCB + lane + 64]);
#pragma unroll
    for (int off = 1; off < 64; off <<= 1) {
      m0 += __shfl_xor(m0, off, 64);
      m1 += __shfl_xor(m1, off, 64);
      mb += __shfl_xor(mb, off, 64);
    }
    m0 += ws[OFF_SB + 0]; m1 += ws[OFF_SB + 1]; mb += ws[OFF_SB + 2];
  }

  // ---- P7: s2[l], insert into hash + bitmap ----
  if (tid < L_) {
    float acc = ws[OFF_PCB + tid];
#pragma unroll 8
    for (int hd = 0; hd < H_ * D_; ++hd) acc = fmaf(att[hd], ws[OFF_PCT + hd * L_ + tid], acc);
    const float SC = 0.08838834764831845f;   // 1/sqrt(E)
    float s2v = (fmaf(sdv[tid] * invn, m0, fmaf(stv[tid], m1, mb)) + acc) * SC;
    unsigned int idx = idxs[tid];
    unsigned int p = idx & 255u;
    while (atomicCAS(&bu.o.hidx[p], 0xFFFFFFFFu, idx) != 0xFFFFFFFFu) p = (p + 1) & 255u;
    bu.o.hval[p] = s2v;
    atomicOr(&bu.o.bitmap[idx >> 5], 1u << (idx & 31));
  }
  __syncthreads();

  // ---- P8: fused zero+scatter coalesced write (each line written once) ----
  float4* o4 = (float4*)(out + base);
#pragma unroll
  for (int t = 0; t < 10; ++t) {
    int i4 = tid + NT * t;
    if (i4 < NI4) {
      unsigned int wbits = (bu.o.bitmap[i4 >> 3] >> ((i4 & 7) * 4)) & 0xFu;
      float4 o = make_float4(0.f, 0.f, 0.f, 0.f);
      if (wbits) {
#pragma unroll
        for (int c = 0; c < 4; ++c) {
          if ((wbits >> c) & 1u) {
            unsigned int idx = (unsigned int)(4 * i4 + c);
            unsigned int p = idx & 255u;
            while (bu.o.hidx[p] != idx) p = (p + 1) & 255u;
            (&o.x)[c] = bu.o.hval[p];
          }
        }
      }
      o4[i4] = o;
    }
  }
}

extern "C" void kernel_launch(void* const* d_in, const int* in_sizes, int n_in,
                              void* d_out, int out_size, void* d_ws, size_t ws_size,
                              hipStream_t stream) {
  const float* dist = (const float*)d_in[0];
  const float* theta = (const float*)d_in[1];
  const float* ninf = (const float*)d_in[2];
  const float* Wi   = (const float*)d_in[3];
  const float* bi   = (const float*)d_in[4];
  const float* cur  = (const float*)d_in[5];
  const float* Wq   = (const float*)d_in[6];
  const float* Wk   = (const float*)d_in[7];
  const float* Wv   = (const float*)d_in[8];
  const float* Wc   = (const float*)d_in[9];
  const float* bcv  = (const float*)d_in[10];
  float* out = (float*)d_out;
  float* ws  = (float*)d_ws;

  precomp<<<dim3(L_ + 1), dim3(128), 0, stream>>>(Wq, Wk, cur, Wi, bi, Wv, Wc, bcv, ws);
  local_att_kernel<<<dim3(B_ * M_), dim3(NT), 0, stream>>>(dist, theta, ninf, ws, out);
}